// Round 3
// baseline (4671.854 us; speedup 1.0000x reference)
//
#include <hip/hip_runtime.h>

#define NN 50000
#define NE 1600000
#define EP (NE + NN)   // edges + self loops
#define IN_DIM 256
#define HIDD 64
#define NCLS 10

// ---- edge_index dtype autodetect: int64 => all odd int32 words are 0 (ids < 2^31) ----
__global__ void detect_mode_k(const int* __restrict__ ei, int* __restrict__ mode) {
    int t = threadIdx.x;  // 64 threads
    int nz = 0;
#pragma unroll
    for (int k = 0; k < 4; ++k) {
        int i = t * 4 + k;                 // i in [0,256)
        if (ei[2 * i + 1] != 0) nz = 1;    // safe: index < 512 << 3.2M words
    }
    unsigned long long b = __ballot(nz);
    if (t == 0) *mode = (b == 0ULL) ? 1 : 0;   // 1 = int64 layout
}

__device__ __forceinline__ void load_edge(const int* __restrict__ ei, int m, int g,
                                          int& s, int& d) {
    if (g < NE) {
        if (m) { s = ei[2 * (size_t)g]; d = ei[2 * ((size_t)NE + g)]; }
        else   { s = ei[g];             d = ei[NE + g]; }
    } else {
        s = d = g - NE;  // self loop
    }
    // harden: clamp so garbage indices can never fault / write OOB
    s = s < 0 ? 0 : (s >= NN ? NN - 1 : s);
    d = d < 0 ? 0 : (d >= NN ? NN - 1 : d);
}

// ---- tiled GEMM: C[M,Ncols] f32 = A[M,K] f32 @ B[K,Ncols] f32 ----
// BM=BN=64, BK=16, 256 threads, 4x4 microtile per thread
__global__ __launch_bounds__(256) void gemm_f32_k(
    const float* __restrict__ A, const float* __restrict__ B, float* __restrict__ C,
    int M, int Ncols, int K) {
    __shared__ float As[16][68];  // [k][m], pad keeps float4 stores conflict-light
    __shared__ float Bs[16][68];  // [k][n]
    const int tid = threadIdx.x;
    const int m0 = blockIdx.y * 64, n0 = blockIdx.x * 64;
    const int ty = tid >> 4, tx = tid & 15;
    const int arow = tid >> 2, acol = (tid & 3) * 4;
    const int brow = tid >> 4, bcol = (tid & 15) * 4;
    float acc[4][4] = {};
    for (int k0 = 0; k0 < K; k0 += 16) {
        float4 a4 = make_float4(0.f, 0.f, 0.f, 0.f);
        if (m0 + arow < M)
            a4 = *(const float4*)(A + (size_t)(m0 + arow) * K + k0 + acol);
        float4 b4 = *(const float4*)(B + (size_t)(k0 + brow) * Ncols + n0 + bcol);
        __syncthreads();
        As[acol + 0][arow] = a4.x;
        As[acol + 1][arow] = a4.y;
        As[acol + 2][arow] = a4.z;
        As[acol + 3][arow] = a4.w;
        *(float4*)&Bs[brow][bcol] = b4;
        __syncthreads();
#pragma unroll
        for (int k = 0; k < 16; ++k) {
            float4 a = *(const float4*)&As[k][ty * 4];
            float4 b = *(const float4*)&Bs[k][tx * 4];
            float aa[4] = {a.x, a.y, a.z, a.w};
            float bb[4] = {b.x, b.y, b.z, b.w};
#pragma unroll
            for (int i = 0; i < 4; ++i)
#pragma unroll
                for (int j = 0; j < 4; ++j) acc[i][j] += aa[i] * bb[j];
        }
    }
#pragma unroll
    for (int i = 0; i < 4; ++i) {
        int row = m0 + ty * 4 + i;
        if (row < M) {
#pragma unroll
            for (int j = 0; j < 4; ++j)
                C[(size_t)row * Ncols + n0 + tx * 4 + j] = acc[i][j];
        }
    }
}

// ---- per-node attention scores: one 64-lane wave per head ----
__global__ void att_scores_k(const float* __restrict__ h, const float* __restrict__ asrc,
                             const float* __restrict__ adst, float* __restrict__ a_s,
                             float* __restrict__ a_d, int H) {
    int n = blockIdx.x, tid = threadIdx.x;  // blockDim.x == H*64
    float v = h[(size_t)n * blockDim.x + tid];
    float ps = v * asrc[tid];
    float pd = v * adst[tid];
#pragma unroll
    for (int off = 32; off; off >>= 1) {
        ps += __shfl_down(ps, off);
        pd += __shfl_down(pd, off);
    }
    if ((tid & 63) == 0) {
        int hh = tid >> 6;
        a_s[(size_t)n * H + hh] = ps;
        a_d[(size_t)n * H + hh] = pd;
    }
}

__device__ __forceinline__ float edge_ex(const float* __restrict__ a_s,
                                         const float* __restrict__ a_d,
                                         int s, int d, int H, int h) {
    float e = a_s[s * H + h] + a_d[d * H + h];
    e = e > 0.f ? e : 0.2f * e;
    e = fminf(e, 60.f);  // harden: no inf; IEEE fmin also squashes NaN -> 60
    return __expf(e);
}

// ---- pass A: denom[dst,h] += ex ----
__global__ __launch_bounds__(256) void edge_den_k(
    const int* __restrict__ ei, const int* __restrict__ mode,
    const float* __restrict__ a_s, const float* __restrict__ a_d,
    float* __restrict__ den, int H) {
    int g = blockIdx.x * blockDim.x + threadIdx.x;
    if (g >= EP) return;
    int m = *mode, s, d;
    load_edge(ei, m, g, s, d);
    for (int h = 0; h < H; ++h)
        atomicAdd(&den[d * H + h], edge_ex(a_s, a_d, s, d, H, h));
}

// ---- pass B: agg[dst,c] += alpha * h[src,c]; thread per (edge, 4 channels) ----
__global__ __launch_bounds__(256) void edge_agg4_k(
    const int* __restrict__ ei, const int* __restrict__ mode,
    const float* __restrict__ a_s, const float* __restrict__ a_d,
    const float* __restrict__ den, const float* __restrict__ hf,
    float* __restrict__ agg, int H, int shift) {
    int gid = blockIdx.x * blockDim.x + threadIdx.x;
    int g = gid >> (shift - 2);
    if (g >= EP) return;
    int c4 = (gid & ((1 << (shift - 2)) - 1)) << 2;  // channel group (within one head)
    int h = c4 >> 6;
    int m = *mode, s, d;
    load_edge(ei, m, g, s, d);
    float ex = edge_ex(a_s, a_d, s, d, H, h);
    float alpha = ex / fmaxf(den[d * H + h], 1e-30f);
    float4 hv = *(const float4*)(hf + ((size_t)s << shift) + c4);
    float* ag = agg + ((size_t)d << shift) + c4;
    atomicAdd(ag + 0, alpha * hv.x);
    atomicAdd(ag + 1, alpha * hv.y);
    atomicAdd(ag + 2, alpha * hv.z);
    atomicAdd(ag + 3, alpha * hv.w);
}

// ---- out = elu(agg + bias) ----
__global__ void bias_elu_k(const float* __restrict__ agg, const float* __restrict__ bias,
                           float* __restrict__ of, int total, int cmask) {
    int i = blockIdx.x * blockDim.x + threadIdx.x;
    if (i >= total) return;
    float v = agg[i] + bias[i & cmask];
    v = v > 0.f ? v : expm1f(v);
    of[i] = v;
}

// ---- head: out[n,cls] = g2[n,:] . Wl[:,cls] + bl[cls] ----
__global__ void head_k(const float* __restrict__ g2, const float* __restrict__ Wl,
                       const float* __restrict__ bl, float* __restrict__ out) {
    int n = blockIdx.x, lane = threadIdx.x;  // 64 lanes
    float v = g2[(size_t)n * HIDD + lane];
#pragma unroll
    for (int cls = 0; cls < NCLS; ++cls) {
        float p = v * Wl[lane * NCLS + cls];
#pragma unroll
        for (int off = 32; off; off >>= 1) p += __shfl_down(p, off);
        if (lane == 0) out[n * NCLS + cls] = p + bl[cls];
    }
}

extern "C" void kernel_launch(void* const* d_in, const int* in_sizes, int n_in,
                              void* d_out, int out_size, void* d_ws, size_t ws_size,
                              hipStream_t stream) {
    const float* x   = (const float*)d_in[0];
    const int*   ei  = (const int*)d_in[1];
    const float* W1  = (const float*)d_in[2];
    const float* as1 = (const float*)d_in[3];
    const float* ad1 = (const float*)d_in[4];
    const float* b1  = (const float*)d_in[5];
    const float* W2  = (const float*)d_in[6];
    const float* as2 = (const float*)d_in[7];
    const float* ad2 = (const float*)d_in[8];
    const float* b2  = (const float*)d_in[9];
    const float* Wl  = (const float*)d_in[10];
    const float* bl  = (const float*)d_in[11];
    float* out = (float*)d_out;

    // ---- workspace layout (floats): 2*N*128 + N*6 + 1 = ~52.4 MB ----
    float* ws = (float*)d_ws;
    size_t o = 0;
    float* bufA = ws + o; o += (size_t)NN * 128;  // h1, then g1, then agg2/g2
    float* bufB = ws + o; o += (size_t)NN * 128;  // agg1, then h2
    float* a_s  = ws + o; o += (size_t)NN * 2;
    float* a_d  = ws + o; o += (size_t)NN * 2;
    float* den  = ws + o; o += (size_t)NN * 2;
    int*   mode = (int*)(ws + o); o += 1;

    detect_mode_k<<<1, 64, 0, stream>>>(ei, mode);

    // ---- layer 1: GATConv(256 -> 64, heads=2, concat) + ELU ----
    hipMemsetAsync(den, 0, (size_t)NN * 2 * sizeof(float), stream);
    hipMemsetAsync(bufB, 0, (size_t)NN * 128 * sizeof(float), stream);
    dim3 grid1(2, (NN + 63) / 64);
    gemm_f32_k<<<grid1, 256, 0, stream>>>(x, W1, bufA, NN, 128, IN_DIM);   // h1 = x@W1
    att_scores_k<<<NN, 128, 0, stream>>>(bufA, as1, ad1, a_s, a_d, 2);
    edge_den_k<<<(EP + 255) / 256, 256, 0, stream>>>(ei, mode, a_s, a_d, den, 2);
    {
        long long tt = (long long)EP * 32;  // 4 channels per thread, 128 ch
        edge_agg4_k<<<(unsigned)((tt + 255) / 256), 256, 0, stream>>>(
            ei, mode, a_s, a_d, den, bufA, bufB, 2, 7);
    }
    bias_elu_k<<<((size_t)NN * 128 + 255) / 256, 256, 0, stream>>>(
        bufB, b1, bufA, NN * 128, 127);  // g1 = elu(agg1+b1) -> bufA

    // ---- layer 2: GATConv(128 -> 64, heads=1) + ELU ----
    dim3 grid2(1, (NN + 63) / 64);
    gemm_f32_k<<<grid2, 256, 0, stream>>>(bufA, W2, bufB, NN, 64, 128);    // h2 -> bufB
    hipMemsetAsync(den, 0, (size_t)NN * sizeof(float), stream);
    hipMemsetAsync(bufA, 0, (size_t)NN * 64 * sizeof(float), stream);      // agg2 -> bufA
    att_scores_k<<<NN, 64, 0, stream>>>(bufB, as2, ad2, a_s, a_d, 1);
    edge_den_k<<<(EP + 255) / 256, 256, 0, stream>>>(ei, mode, a_s, a_d, den, 1);
    {
        long long tt = (long long)EP * 16;  // 4 channels per thread, 64 ch
        edge_agg4_k<<<(unsigned)((tt + 255) / 256), 256, 0, stream>>>(
            ei, mode, a_s, a_d, den, bufB, bufA, 1, 6);
    }
    bias_elu_k<<<((size_t)NN * 64 + 255) / 256, 256, 0, stream>>>(
        bufA, b2, bufA, NN * 64, 63);  // g2 in-place

    // ---- linear head ----
    head_k<<<NN, 64, 0, stream>>>(bufA, Wl, bl, out);
}

// Round 4
// 701.930 us; speedup vs baseline: 6.6557x; 6.6557x over previous
//
#include <hip/hip_runtime.h>

#define NN 50000
#define NE 1600000
#define EP (NE + NN)   // edges + self loops
#define IN_DIM 256
#define HIDD 64
#define NCLS 10
#define NB_SCAN ((NN + 255) / 256)   // 196 blocks for the degree scan

// ---- edge_index dtype autodetect: int64 => all odd int32 words are 0 (ids < 2^31) ----
__global__ void detect_mode_k(const int* __restrict__ ei, int* __restrict__ mode) {
    int t = threadIdx.x;  // 64 threads
    int nz = 0;
#pragma unroll
    for (int k = 0; k < 4; ++k) {
        int i = t * 4 + k;
        if (ei[2 * i + 1] != 0) nz = 1;
    }
    unsigned long long b = __ballot(nz);
    if (t == 0) *mode = (b == 0ULL) ? 1 : 0;   // 1 = int64 layout
}

__device__ __forceinline__ void load_edge(const int* __restrict__ ei, int m, int g,
                                          int& s, int& d) {
    if (g < NE) {
        if (m) { s = ei[2 * (size_t)g]; d = ei[2 * ((size_t)NE + g)]; }
        else   { s = ei[g];             d = ei[NE + g]; }
    } else {
        s = d = g - NE;  // self loop
    }
    s = s < 0 ? 0 : (s >= NN ? NN - 1 : s);
    d = d < 0 ? 0 : (d >= NN ? NN - 1 : d);
}

// ---- CSR build ----
__global__ __launch_bounds__(256) void deg_count_k(const int* __restrict__ ei,
                                                   const int* __restrict__ mode,
                                                   int* __restrict__ deg) {
    int g = blockIdx.x * blockDim.x + threadIdx.x;
    if (g >= EP) return;
    int m = *mode, s, d;
    load_edge(ei, m, g, s, d);
    atomicAdd(&deg[d], 1);
}

__global__ __launch_bounds__(256) void scan1_k(const int* __restrict__ deg,
                                               int* __restrict__ excl,
                                               int* __restrict__ bsums) {
    __shared__ int sh[256];
    int t = threadIdx.x, b = blockIdx.x, i = b * 256 + t;
    int v = (i < NN) ? deg[i] : 0;
    sh[t] = v;
    __syncthreads();
    for (int off = 1; off < 256; off <<= 1) {
        int x = (t >= off) ? sh[t - off] : 0;
        __syncthreads();
        sh[t] += x;
        __syncthreads();
    }
    if (i < NN) excl[i] = sh[t] - v;
    if (t == 255) bsums[b] = sh[t];
}

__global__ __launch_bounds__(256) void scan2_k(int* __restrict__ bsums) {
    __shared__ int sh[256];
    int t = threadIdx.x;
    int v = (t < NB_SCAN) ? bsums[t] : 0;
    sh[t] = v;
    __syncthreads();
    for (int off = 1; off < 256; off <<= 1) {
        int x = (t >= off) ? sh[t - off] : 0;
        __syncthreads();
        sh[t] += x;
        __syncthreads();
    }
    if (t < NB_SCAN) bsums[t] = sh[t] - v;  // exclusive
}

__global__ __launch_bounds__(256) void scan3_k(const int* __restrict__ excl,
                                               const int* __restrict__ bsums,
                                               int* __restrict__ row_ptr) {
    int t = threadIdx.x, b = blockIdx.x, i = b * 256 + t;
    if (i < NN) row_ptr[i] = excl[i] + bsums[b];
    if (i == 0) row_ptr[NN] = EP;
}

__global__ __launch_bounds__(256) void scatter_k(const int* __restrict__ ei,
                                                 const int* __restrict__ mode,
                                                 const int* __restrict__ row_ptr,
                                                 int* __restrict__ cursor,
                                                 int* __restrict__ csr_src) {
    int g = blockIdx.x * blockDim.x + threadIdx.x;
    if (g >= EP) return;
    int m = *mode, s, d;
    load_edge(ei, m, g, s, d);
    int pos = atomicAdd(&cursor[d], 1);
    csr_src[row_ptr[d] + pos] = s;
}

// ---- tiled GEMM: C[M,Ncols] f32 = A[M,K] f32 @ B[K,Ncols] f32 ----
__global__ __launch_bounds__(256) void gemm_f32_k(
    const float* __restrict__ A, const float* __restrict__ B, float* __restrict__ C,
    int M, int Ncols, int K) {
    __shared__ float As[16][68];
    __shared__ float Bs[16][68];
    const int tid = threadIdx.x;
    const int m0 = blockIdx.y * 64, n0 = blockIdx.x * 64;
    const int ty = tid >> 4, tx = tid & 15;
    const int arow = tid >> 2, acol = (tid & 3) * 4;
    const int brow = tid >> 4, bcol = (tid & 15) * 4;
    float acc[4][4] = {};
    for (int k0 = 0; k0 < K; k0 += 16) {
        float4 a4 = make_float4(0.f, 0.f, 0.f, 0.f);
        if (m0 + arow < M)
            a4 = *(const float4*)(A + (size_t)(m0 + arow) * K + k0 + acol);
        float4 b4 = *(const float4*)(B + (size_t)(k0 + brow) * Ncols + n0 + bcol);
        __syncthreads();
        As[acol + 0][arow] = a4.x;
        As[acol + 1][arow] = a4.y;
        As[acol + 2][arow] = a4.z;
        As[acol + 3][arow] = a4.w;
        *(float4*)&Bs[brow][bcol] = b4;
        __syncthreads();
#pragma unroll
        for (int k = 0; k < 16; ++k) {
            float4 a = *(const float4*)&As[k][ty * 4];
            float4 b = *(const float4*)&Bs[k][tx * 4];
            float aa[4] = {a.x, a.y, a.z, a.w};
            float bb[4] = {b.x, b.y, b.z, b.w};
#pragma unroll
            for (int i = 0; i < 4; ++i)
#pragma unroll
                for (int j = 0; j < 4; ++j) acc[i][j] += aa[i] * bb[j];
        }
    }
#pragma unroll
    for (int i = 0; i < 4; ++i) {
        int row = m0 + ty * 4 + i;
        if (row < M) {
#pragma unroll
            for (int j = 0; j < 4; ++j)
                C[(size_t)row * Ncols + n0 + tx * 4 + j] = acc[i][j];
        }
    }
}

// ---- per-node attention scores: one 64-lane wave per head ----
__global__ void att_scores_k(const float* __restrict__ h, const float* __restrict__ asrc,
                             const float* __restrict__ adst, float* __restrict__ a_s,
                             float* __restrict__ a_d, int H) {
    int n = blockIdx.x, tid = threadIdx.x;  // blockDim.x == H*64
    float v = h[(size_t)n * blockDim.x + tid];
    float ps = v * asrc[tid];
    float pd = v * adst[tid];
#pragma unroll
    for (int off = 32; off; off >>= 1) {
        ps += __shfl_down(ps, off);
        pd += __shfl_down(pd, off);
    }
    if ((tid & 63) == 0) {
        int hh = tid >> 6;
        a_s[(size_t)n * H + hh] = ps;
        a_d[(size_t)n * H + hh] = pd;
    }
}

// ---- fused gather: out[n,c] = elu( sum_e alpha_e * h[src_e, c] + bias[c] ) ----
// blockDim = CH (= H*64); wave hh handles head hh; lane = channel within head.
template <int CH>
__global__ __launch_bounds__(CH) void gat_gather_k(
    const int* __restrict__ row_ptr, const int* __restrict__ csr_src,
    const float* __restrict__ a_s, const float* __restrict__ a_d,
    const float* __restrict__ h, const float* __restrict__ bias,
    float* __restrict__ outg, int H) {
    int n = blockIdx.x;
    int tid = threadIdx.x;
    int hh = tid >> 6;
    int lane = tid & 63;
    int r0 = row_ptr[n], r1 = row_ptr[n + 1];
    float adn = a_d[n * H + hh];
    float den = 0.f, acc = 0.f;
    for (int base = r0; base < r1; base += 64) {
        int cnt = min(64, r1 - base);
        int sl = (base + lane < r1) ? csr_src[base + lane] : 0;
        for (int j = 0; j < cnt; ++j) {
            int s = __shfl(sl, j);
            float e = a_s[s * H + hh] + adn;
            e = e > 0.f ? e : 0.2f * e;
            e = fminf(e, 60.f);
            float ex = __expf(e);
            float hv = h[(size_t)s * CH + tid];
            den += ex;
            acc += ex * hv;
        }
    }
    float v = acc / den + bias[tid];   // den >= exp(self-loop) > 0
    v = v > 0.f ? v : expm1f(v);
    outg[(size_t)n * CH + tid] = v;
}

// ---- head: out[n,cls] = g2[n,:] . Wl[:,cls] + bl[cls] ----
__global__ void head_k(const float* __restrict__ g2, const float* __restrict__ Wl,
                       const float* __restrict__ bl, float* __restrict__ out) {
    int n = blockIdx.x, lane = threadIdx.x;  // 64 lanes
    float v = g2[(size_t)n * HIDD + lane];
#pragma unroll
    for (int cls = 0; cls < NCLS; ++cls) {
        float p = v * Wl[lane * NCLS + cls];
#pragma unroll
        for (int off = 32; off; off >>= 1) p += __shfl_down(p, off);
        if (lane == 0) out[n * NCLS + cls] = p + bl[cls];
    }
}

extern "C" void kernel_launch(void* const* d_in, const int* in_sizes, int n_in,
                              void* d_out, int out_size, void* d_ws, size_t ws_size,
                              hipStream_t stream) {
    const float* x   = (const float*)d_in[0];
    const int*   ei  = (const int*)d_in[1];
    const float* W1  = (const float*)d_in[2];
    const float* as1 = (const float*)d_in[3];
    const float* ad1 = (const float*)d_in[4];
    const float* b1  = (const float*)d_in[5];
    const float* W2  = (const float*)d_in[6];
    const float* as2 = (const float*)d_in[7];
    const float* ad2 = (const float*)d_in[8];
    const float* b2  = (const float*)d_in[9];
    const float* Wl  = (const float*)d_in[10];
    const float* bl  = (const float*)d_in[11];
    float* out = (float*)d_out;

    // ---- workspace layout: ~59.4 MB ----
    float* ws = (float*)d_ws;
    size_t o = 0;
    float* bufA = ws + o; o += (size_t)NN * 128;   // h1 / h2
    float* bufB = ws + o; o += (size_t)NN * 128;   // g1 / g2
    float* a_s  = ws + o; o += (size_t)NN * 2;
    float* a_d  = ws + o; o += (size_t)NN * 2;
    int* ints = (int*)(ws + o);
    size_t io = 0;
    int* deg     = ints + io; io += NN;
    int* cursor  = ints + io; io += NN;
    int* excl    = ints + io; io += NN;
    int* bsums   = ints + io; io += 256;
    int* row_ptr = ints + io; io += NN + 1;
    int* csr_src = ints + io; io += EP;
    int* mode    = ints + io; io += 1;

    detect_mode_k<<<1, 64, 0, stream>>>(ei, mode);

    // ---- CSR of incoming edges (shared by both layers) ----
    hipMemsetAsync(deg, 0, NN * sizeof(int), stream);
    hipMemsetAsync(cursor, 0, NN * sizeof(int), stream);
    deg_count_k<<<(EP + 255) / 256, 256, 0, stream>>>(ei, mode, deg);
    scan1_k<<<NB_SCAN, 256, 0, stream>>>(deg, excl, bsums);
    scan2_k<<<1, 256, 0, stream>>>(bsums);
    scan3_k<<<NB_SCAN, 256, 0, stream>>>(excl, bsums, row_ptr);
    scatter_k<<<(EP + 255) / 256, 256, 0, stream>>>(ei, mode, row_ptr, cursor, csr_src);

    // ---- layer 1: GATConv(256 -> 64, heads=2, concat) + ELU ----
    dim3 grid1(2, (NN + 63) / 64);
    gemm_f32_k<<<grid1, 256, 0, stream>>>(x, W1, bufA, NN, 128, IN_DIM);   // h1
    att_scores_k<<<NN, 128, 0, stream>>>(bufA, as1, ad1, a_s, a_d, 2);
    gat_gather_k<128><<<NN, 128, 0, stream>>>(row_ptr, csr_src, a_s, a_d,
                                              bufA, b1, bufB, 2);          // g1

    // ---- layer 2: GATConv(128 -> 64, heads=1) + ELU ----
    dim3 grid2(1, (NN + 63) / 64);
    gemm_f32_k<<<grid2, 256, 0, stream>>>(bufB, W2, bufA, NN, 64, 128);    // h2
    att_scores_k<<<NN, 64, 0, stream>>>(bufA, as2, ad2, a_s, a_d, 1);
    gat_gather_k<64><<<NN, 64, 0, stream>>>(row_ptr, csr_src, a_s, a_d,
                                            bufA, b2, bufB, 1);            // g2

    // ---- linear head ----
    head_k<<<NN, 64, 0, stream>>>(bufB, Wl, bl, out);
}

// Round 5
// 628.998 us; speedup vs baseline: 7.4275x; 1.1159x over previous
//
#include <hip/hip_runtime.h>

#define NN 50000
#define NE 1600000
#define EP (NE + NN)   // edges + self loops
#define IN_DIM 256
#define HIDD 64
#define NCLS 10
#define NB_SCAN ((NN + 255) / 256)   // 196 blocks for the degree scan

// ---- edge_index dtype autodetect: int64 => all odd int32 words are 0 (ids < 2^31) ----
__global__ void detect_mode_k(const int* __restrict__ ei, int* __restrict__ mode) {
    int t = threadIdx.x;  // 64 threads
    int nz = 0;
#pragma unroll
    for (int k = 0; k < 4; ++k) {
        int i = t * 4 + k;
        if (ei[2 * i + 1] != 0) nz = 1;
    }
    unsigned long long b = __ballot(nz);
    if (t == 0) *mode = (b == 0ULL) ? 1 : 0;   // 1 = int64 layout
}

__device__ __forceinline__ void load_edge(const int* __restrict__ ei, int m, int g,
                                          int& s, int& d) {
    if (g < NE) {
        if (m) { s = ei[2 * (size_t)g]; d = ei[2 * ((size_t)NE + g)]; }
        else   { s = ei[g];             d = ei[NE + g]; }
    } else {
        s = d = g - NE;  // self loop
    }
    s = s < 0 ? 0 : (s >= NN ? NN - 1 : s);
    d = d < 0 ? 0 : (d >= NN ? NN - 1 : d);
}

// ---- CSR build ----
__global__ __launch_bounds__(256) void deg_count_k(const int* __restrict__ ei,
                                                   const int* __restrict__ mode,
                                                   int* __restrict__ deg) {
    int g = blockIdx.x * blockDim.x + threadIdx.x;
    if (g >= EP) return;
    int m = *mode, s, d;
    load_edge(ei, m, g, s, d);
    atomicAdd(&deg[d], 1);
}

__global__ __launch_bounds__(256) void scan1_k(const int* __restrict__ deg,
                                               int* __restrict__ excl,
                                               int* __restrict__ bsums) {
    __shared__ int sh[256];
    int t = threadIdx.x, b = blockIdx.x, i = b * 256 + t;
    int v = (i < NN) ? deg[i] : 0;
    sh[t] = v;
    __syncthreads();
    for (int off = 1; off < 256; off <<= 1) {
        int x = (t >= off) ? sh[t - off] : 0;
        __syncthreads();
        sh[t] += x;
        __syncthreads();
    }
    if (i < NN) excl[i] = sh[t] - v;
    if (t == 255) bsums[b] = sh[t];
}

__global__ __launch_bounds__(256) void scan2_k(int* __restrict__ bsums) {
    __shared__ int sh[256];
    int t = threadIdx.x;
    int v = (t < NB_SCAN) ? bsums[t] : 0;
    sh[t] = v;
    __syncthreads();
    for (int off = 1; off < 256; off <<= 1) {
        int x = (t >= off) ? sh[t - off] : 0;
        __syncthreads();
        sh[t] += x;
        __syncthreads();
    }
    if (t < NB_SCAN) bsums[t] = sh[t] - v;  // exclusive
}

__global__ __launch_bounds__(256) void scan3_k(const int* __restrict__ excl,
                                               const int* __restrict__ bsums,
                                               int* __restrict__ row_ptr) {
    int t = threadIdx.x, b = blockIdx.x, i = b * 256 + t;
    if (i < NN) row_ptr[i] = excl[i] + bsums[b];
    if (i == 0) row_ptr[NN] = EP;
}

__global__ __launch_bounds__(256) void scatter_k(const int* __restrict__ ei,
                                                 const int* __restrict__ mode,
                                                 const int* __restrict__ row_ptr,
                                                 int* __restrict__ cursor,
                                                 int* __restrict__ csr_src) {
    int g = blockIdx.x * blockDim.x + threadIdx.x;
    if (g >= EP) return;
    int m = *mode, s, d;
    load_edge(ei, m, g, s, d);
    int pos = atomicAdd(&cursor[d], 1);
    csr_src[row_ptr[d] + pos] = s;
}

// ---- tiled GEMM: C[M,Ncols] f32 = A[M,K] f32 @ B[K,Ncols] f32 ----
__global__ __launch_bounds__(256) void gemm_f32_k(
    const float* __restrict__ A, const float* __restrict__ B, float* __restrict__ C,
    int M, int Ncols, int K) {
    __shared__ float As[16][68];
    __shared__ float Bs[16][68];
    const int tid = threadIdx.x;
    const int m0 = blockIdx.y * 64, n0 = blockIdx.x * 64;
    const int ty = tid >> 4, tx = tid & 15;
    const int arow = tid >> 2, acol = (tid & 3) * 4;
    const int brow = tid >> 4, bcol = (tid & 15) * 4;
    float acc[4][4] = {};
    for (int k0 = 0; k0 < K; k0 += 16) {
        float4 a4 = make_float4(0.f, 0.f, 0.f, 0.f);
        if (m0 + arow < M)
            a4 = *(const float4*)(A + (size_t)(m0 + arow) * K + k0 + acol);
        float4 b4 = *(const float4*)(B + (size_t)(k0 + brow) * Ncols + n0 + bcol);
        __syncthreads();
        As[acol + 0][arow] = a4.x;
        As[acol + 1][arow] = a4.y;
        As[acol + 2][arow] = a4.z;
        As[acol + 3][arow] = a4.w;
        *(float4*)&Bs[brow][bcol] = b4;
        __syncthreads();
#pragma unroll
        for (int k = 0; k < 16; ++k) {
            float4 a = *(const float4*)&As[k][ty * 4];
            float4 b = *(const float4*)&Bs[k][tx * 4];
            float aa[4] = {a.x, a.y, a.z, a.w};
            float bb[4] = {b.x, b.y, b.z, b.w};
#pragma unroll
            for (int i = 0; i < 4; ++i)
#pragma unroll
                for (int j = 0; j < 4; ++j) acc[i][j] += aa[i] * bb[j];
        }
    }
#pragma unroll
    for (int i = 0; i < 4; ++i) {
        int row = m0 + ty * 4 + i;
        if (row < M) {
#pragma unroll
            for (int j = 0; j < 4; ++j)
                C[(size_t)row * Ncols + n0 + tx * 4 + j] = acc[i][j];
        }
    }
}

// ---- per-node attention scores: one 64-lane wave per head ----
__global__ void att_scores_k(const float* __restrict__ h, const float* __restrict__ asrc,
                             const float* __restrict__ adst, float* __restrict__ a_s,
                             float* __restrict__ a_d, int H) {
    int n = blockIdx.x, tid = threadIdx.x;  // blockDim.x == H*64
    float v = h[(size_t)n * blockDim.x + tid];
    float ps = v * asrc[tid];
    float pd = v * adst[tid];
#pragma unroll
    for (int off = 32; off; off >>= 1) {
        ps += __shfl_down(ps, off);
        pd += __shfl_down(pd, off);
    }
    if ((tid & 63) == 0) {
        int hh = tid >> 6;
        a_s[(size_t)n * H + hh] = ps;
        a_d[(size_t)n * H + hh] = pd;
    }
}

// ---- fused gather: one WAVE per node; VEC = CH/64 floats per lane ----
// Lane-parallel softmax: each lane computes ex for one edge of the chunk
// (gather a_s, leaky-relu, exp all in parallel), then a lean j-loop does
// shfl(s), shfl(ex), coalesced h-row load, fma.
template <int CH, int H>
__global__ __launch_bounds__(256) void gat_gather_k(
    const int* __restrict__ row_ptr, const int* __restrict__ csr_src,
    const float* __restrict__ a_s, const float* __restrict__ a_d,
    const float* __restrict__ h, const float* __restrict__ bias,
    float* __restrict__ outg) {
    constexpr int VEC = CH / 64;
    int n = (blockIdx.x * blockDim.x + threadIdx.x) >> 6;  // global wave id = node
    int lane = threadIdx.x & 63;
    if (n >= NN) return;  // wave-uniform exit
    int r0 = row_ptr[n], r1 = row_ptr[n + 1];
    const int myh = (lane * VEC) >> 6;  // head owning this lane's channels

    float adn[H];
#pragma unroll
    for (int hh = 0; hh < H; ++hh) adn[hh] = a_d[n * H + hh];

    float denp[H];
#pragma unroll
    for (int hh = 0; hh < H; ++hh) denp[hh] = 0.f;
    float acc[VEC];
#pragma unroll
    for (int v = 0; v < VEC; ++v) acc[v] = 0.f;

    for (int base = r0; base < r1; base += 64) {
        int cnt = min(64, r1 - base);
        int idx = base + lane;
        bool act = idx < r1;
        int sl = act ? csr_src[idx] : 0;
        float exl[H];
#pragma unroll
        for (int hh = 0; hh < H; ++hh) {
            float e = a_s[sl * H + hh] + adn[hh];
            e = e > 0.f ? e : 0.2f * e;
            e = fminf(e, 60.f);
            float ex = __expf(e);
            exl[hh] = act ? ex : 0.f;
            denp[hh] += exl[hh];
        }
#pragma unroll 2
        for (int j = 0; j < cnt; ++j) {
            int s = __shfl(sl, j);
            float exv;
            if (H == 1) {
                exv = __shfl(exl[0], j);
            } else {
                float e0 = __shfl(exl[0], j);
                float e1 = __shfl(exl[1], j);
                exv = myh ? e1 : e0;
            }
            const float* hp = h + (size_t)s * CH + lane * VEC;
            if (VEC == 2) {
                float2 hv = *(const float2*)hp;
                acc[0] += exv * hv.x;
                acc[1] += exv * hv.y;
            } else {
                acc[0] += exv * hp[0];
            }
        }
    }

    // butterfly-reduce denominators across the wave (all lanes get the sum)
    float den[H];
#pragma unroll
    for (int hh = 0; hh < H; ++hh) {
        float dsum = denp[hh];
#pragma unroll
        for (int off = 32; off; off >>= 1) dsum += __shfl_xor(dsum, off);
        den[hh] = dsum;
    }
    float dn = den[myh];  // den >= exp(self-loop) > 0

    // epilogue: alpha-normalize + bias + ELU, vector store
    if (VEC == 2) {
        int c = lane * 2;
        float2 bv = *(const float2*)(bias + c);
        float v0 = acc[0] / dn + bv.x;
        float v1 = acc[1] / dn + bv.y;
        v0 = v0 > 0.f ? v0 : expm1f(v0);
        v1 = v1 > 0.f ? v1 : expm1f(v1);
        *(float2*)(outg + (size_t)n * CH + c) = make_float2(v0, v1);
    } else {
        float v0 = acc[0] / dn + bias[lane];
        v0 = v0 > 0.f ? v0 : expm1f(v0);
        outg[(size_t)n * CH + lane] = v0;
    }
}

// ---- head: out[n,cls] = g2[n,:] . Wl[:,cls] + bl[cls] ----
__global__ void head_k(const float* __restrict__ g2, const float* __restrict__ Wl,
                       const float* __restrict__ bl, float* __restrict__ out) {
    int n = blockIdx.x, lane = threadIdx.x;  // 64 lanes
    float v = g2[(size_t)n * HIDD + lane];
#pragma unroll
    for (int cls = 0; cls < NCLS; ++cls) {
        float p = v * Wl[lane * NCLS + cls];
#pragma unroll
        for (int off = 32; off; off >>= 1) p += __shfl_down(p, off);
        if (lane == 0) out[n * NCLS + cls] = p + bl[cls];
    }
}

extern "C" void kernel_launch(void* const* d_in, const int* in_sizes, int n_in,
                              void* d_out, int out_size, void* d_ws, size_t ws_size,
                              hipStream_t stream) {
    const float* x   = (const float*)d_in[0];
    const int*   ei  = (const int*)d_in[1];
    const float* W1  = (const float*)d_in[2];
    const float* as1 = (const float*)d_in[3];
    const float* ad1 = (const float*)d_in[4];
    const float* b1  = (const float*)d_in[5];
    const float* W2  = (const float*)d_in[6];
    const float* as2 = (const float*)d_in[7];
    const float* ad2 = (const float*)d_in[8];
    const float* b2  = (const float*)d_in[9];
    const float* Wl  = (const float*)d_in[10];
    const float* bl  = (const float*)d_in[11];
    float* out = (float*)d_out;

    // ---- workspace layout: ~59.4 MB ----
    float* ws = (float*)d_ws;
    size_t o = 0;
    float* bufA = ws + o; o += (size_t)NN * 128;   // h1 / h2
    float* bufB = ws + o; o += (size_t)NN * 128;   // g1 / g2
    float* a_s  = ws + o; o += (size_t)NN * 2;
    float* a_d  = ws + o; o += (size_t)NN * 2;
    int* ints = (int*)(ws + o);
    size_t io = 0;
    int* deg     = ints + io; io += NN;
    int* cursor  = ints + io; io += NN;
    int* excl    = ints + io; io += NN;
    int* bsums   = ints + io; io += 256;
    int* row_ptr = ints + io; io += NN + 1;
    int* csr_src = ints + io; io += EP;
    int* mode    = ints + io; io += 1;

    detect_mode_k<<<1, 64, 0, stream>>>(ei, mode);

    // ---- CSR of incoming edges (shared by both layers) ----
    hipMemsetAsync(deg, 0, NN * sizeof(int), stream);
    hipMemsetAsync(cursor, 0, NN * sizeof(int), stream);
    deg_count_k<<<(EP + 255) / 256, 256, 0, stream>>>(ei, mode, deg);
    scan1_k<<<NB_SCAN, 256, 0, stream>>>(deg, excl, bsums);
    scan2_k<<<1, 256, 0, stream>>>(bsums);
    scan3_k<<<NB_SCAN, 256, 0, stream>>>(excl, bsums, row_ptr);
    scatter_k<<<(EP + 255) / 256, 256, 0, stream>>>(ei, mode, row_ptr, cursor, csr_src);

    const int gatherBlocks = (NN + 3) / 4;  // 4 waves (nodes) per 256-thread block

    // ---- layer 1: GATConv(256 -> 64, heads=2, concat) + ELU ----
    dim3 grid1(2, (NN + 63) / 64);
    gemm_f32_k<<<grid1, 256, 0, stream>>>(x, W1, bufA, NN, 128, IN_DIM);   // h1
    att_scores_k<<<NN, 128, 0, stream>>>(bufA, as1, ad1, a_s, a_d, 2);
    gat_gather_k<128, 2><<<gatherBlocks, 256, 0, stream>>>(
        row_ptr, csr_src, a_s, a_d, bufA, b1, bufB);                       // g1

    // ---- layer 2: GATConv(128 -> 64, heads=1) + ELU ----
    dim3 grid2(1, (NN + 63) / 64);
    gemm_f32_k<<<grid2, 256, 0, stream>>>(bufB, W2, bufA, NN, 64, 128);    // h2
    att_scores_k<<<NN, 64, 0, stream>>>(bufA, as2, ad2, a_s, a_d, 1);
    gat_gather_k<64, 1><<<gatherBlocks, 256, 0, stream>>>(
        row_ptr, csr_src, a_s, a_d, bufA, b2, bufB);                       // g2

    // ---- linear head ----
    head_k<<<NN, 64, 0, stream>>>(bufB, Wl, bl, out);
}

// Round 6
// 593.026 us; speedup vs baseline: 7.8780x; 1.0607x over previous
//
#include <hip/hip_runtime.h>

#define NN 50000
#define NE 1600000
#define EP (NE + NN)   // edges + self loops
#define IN_DIM 256
#define HIDD 64
#define NCLS 10
#define NB_SCAN ((NN + 255) / 256)   // 196 blocks for the degree scan

typedef unsigned short u16;

__device__ __forceinline__ float b2f(u16 v) { return __uint_as_float(((unsigned)v) << 16); }
__device__ __forceinline__ u16 f2b(float f) {
    unsigned u = __float_as_uint(f);
    unsigned r = (u + 0x7FFFu + ((u >> 16) & 1u)) >> 16;
    return (u16)r;
}

// ---- edge_index dtype autodetect: int64 => all odd int32 words are 0 (ids < 2^31) ----
__global__ void detect_mode_k(const int* __restrict__ ei, int* __restrict__ mode) {
    int t = threadIdx.x;  // 64 threads
    int nz = 0;
#pragma unroll
    for (int k = 0; k < 4; ++k) {
        int i = t * 4 + k;
        if (ei[2 * i + 1] != 0) nz = 1;
    }
    unsigned long long b = __ballot(nz);
    if (t == 0) *mode = (b == 0ULL) ? 1 : 0;   // 1 = int64 layout
}

__device__ __forceinline__ void load_edge(const int* __restrict__ ei, int m, int g,
                                          int& s, int& d) {
    if (g < NE) {
        if (m) { s = ei[2 * (size_t)g]; d = ei[2 * ((size_t)NE + g)]; }
        else   { s = ei[g];             d = ei[NE + g]; }
    } else {
        s = d = g - NE;  // self loop
    }
    s = s < 0 ? 0 : (s >= NN ? NN - 1 : s);
    d = d < 0 ? 0 : (d >= NN ? NN - 1 : d);
}

// ---- CSR build ----
__global__ __launch_bounds__(256) void deg_count_k(const int* __restrict__ ei,
                                                   const int* __restrict__ mode,
                                                   int* __restrict__ deg) {
    int g = blockIdx.x * blockDim.x + threadIdx.x;
    if (g >= EP) return;
    int m = *mode, s, d;
    load_edge(ei, m, g, s, d);
    atomicAdd(&deg[d], 1);
}

__global__ __launch_bounds__(256) void scan1_k(const int* __restrict__ deg,
                                               int* __restrict__ excl,
                                               int* __restrict__ bsums) {
    __shared__ int sh[256];
    int t = threadIdx.x, b = blockIdx.x, i = b * 256 + t;
    int v = (i < NN) ? deg[i] : 0;
    sh[t] = v;
    __syncthreads();
    for (int off = 1; off < 256; off <<= 1) {
        int x = (t >= off) ? sh[t - off] : 0;
        __syncthreads();
        sh[t] += x;
        __syncthreads();
    }
    if (i < NN) excl[i] = sh[t] - v;
    if (t == 255) bsums[b] = sh[t];
}

__global__ __launch_bounds__(256) void scan2_k(int* __restrict__ bsums) {
    __shared__ int sh[256];
    int t = threadIdx.x;
    int v = (t < NB_SCAN) ? bsums[t] : 0;
    sh[t] = v;
    __syncthreads();
    for (int off = 1; off < 256; off <<= 1) {
        int x = (t >= off) ? sh[t - off] : 0;
        __syncthreads();
        sh[t] += x;
        __syncthreads();
    }
    if (t < NB_SCAN) bsums[t] = sh[t] - v;  // exclusive
}

__global__ __launch_bounds__(256) void scan3_k(const int* __restrict__ excl,
                                               const int* __restrict__ bsums,
                                               int* __restrict__ row_ptr) {
    int t = threadIdx.x, b = blockIdx.x, i = b * 256 + t;
    if (i < NN) row_ptr[i] = excl[i] + bsums[b];
    if (i == 0) row_ptr[NN] = EP;
}

__global__ __launch_bounds__(256) void scatter_k(const int* __restrict__ ei,
                                                 const int* __restrict__ mode,
                                                 const int* __restrict__ row_ptr,
                                                 int* __restrict__ cursor,
                                                 int* __restrict__ csr_src) {
    int g = blockIdx.x * blockDim.x + threadIdx.x;
    if (g >= EP) return;
    int m = *mode, s, d;
    load_edge(ei, m, g, s, d);
    int pos = atomicAdd(&cursor[d], 1);
    csr_src[row_ptr[d] + pos] = s;
}

// ---- tiled GEMM: C[M,Ncols] bf16 = A[M,K] f32 @ B[K,Ncols] f32 (f32 acc) ----
__global__ __launch_bounds__(256) void gemm_f32b_k(
    const float* __restrict__ A, const float* __restrict__ B, u16* __restrict__ C,
    int M, int Ncols, int K) {
    __shared__ float As[16][68];
    __shared__ float Bs[16][68];
    const int tid = threadIdx.x;
    const int m0 = blockIdx.y * 64, n0 = blockIdx.x * 64;
    const int ty = tid >> 4, tx = tid & 15;
    const int arow = tid >> 2, acol = (tid & 3) * 4;
    const int brow = tid >> 4, bcol = (tid & 15) * 4;
    float acc[4][4] = {};
    for (int k0 = 0; k0 < K; k0 += 16) {
        float4 a4 = make_float4(0.f, 0.f, 0.f, 0.f);
        if (m0 + arow < M)
            a4 = *(const float4*)(A + (size_t)(m0 + arow) * K + k0 + acol);
        float4 b4 = *(const float4*)(B + (size_t)(k0 + brow) * Ncols + n0 + bcol);
        __syncthreads();
        As[acol + 0][arow] = a4.x;
        As[acol + 1][arow] = a4.y;
        As[acol + 2][arow] = a4.z;
        As[acol + 3][arow] = a4.w;
        *(float4*)&Bs[brow][bcol] = b4;
        __syncthreads();
#pragma unroll
        for (int k = 0; k < 16; ++k) {
            float4 a = *(const float4*)&As[k][ty * 4];
            float4 b = *(const float4*)&Bs[k][tx * 4];
            float aa[4] = {a.x, a.y, a.z, a.w};
            float bb[4] = {b.x, b.y, b.z, b.w};
#pragma unroll
            for (int i = 0; i < 4; ++i)
#pragma unroll
                for (int j = 0; j < 4; ++j) acc[i][j] += aa[i] * bb[j];
        }
    }
#pragma unroll
    for (int i = 0; i < 4; ++i) {
        int row = m0 + ty * 4 + i;
        if (row < M) {
            ushort4 cv;
            cv.x = f2b(acc[i][0]); cv.y = f2b(acc[i][1]);
            cv.z = f2b(acc[i][2]); cv.w = f2b(acc[i][3]);
            *(ushort4*)(C + (size_t)row * Ncols + n0 + tx * 4) = cv;
        }
    }
}

// ---- per-node attention scores (bf16 h): one 64-lane wave per head ----
__global__ void att_scores_k(const u16* __restrict__ h, const float* __restrict__ asrc,
                             const float* __restrict__ adst, float* __restrict__ a_s,
                             float* __restrict__ a_d, int H) {
    int n = blockIdx.x, tid = threadIdx.x;  // blockDim.x == H*64
    float v = b2f(h[(size_t)n * blockDim.x + tid]);
    float ps = v * asrc[tid];
    float pd = v * adst[tid];
#pragma unroll
    for (int off = 32; off; off >>= 1) {
        ps += __shfl_down(ps, off);
        pd += __shfl_down(pd, off);
    }
    if ((tid & 63) == 0) {
        int hh = tid >> 6;
        a_s[(size_t)n * H + hh] = ps;
        a_d[(size_t)n * H + hh] = pd;
    }
}

// ---- fused gather (bf16 h): one WAVE per node; VEC = CH/64 bf16 per lane ----
// Lane-parallel softmax (one exp per edge, across lanes), lean j-loop:
// shfl(s), shfl(ex), coalesced bf16 h-row load, fma. Optional fused head.
template <int CH, int H, bool HEAD>
__global__ __launch_bounds__(256) void gat_gather_k(
    const int* __restrict__ row_ptr, const int* __restrict__ csr_src,
    const float* __restrict__ a_s, const float* __restrict__ a_d,
    const u16* __restrict__ h, const float* __restrict__ bias,
    float* __restrict__ outg, const float* __restrict__ Wl,
    const float* __restrict__ bl, float* __restrict__ outh) {
    constexpr int VEC = CH / 64;
    int n = (blockIdx.x * blockDim.x + threadIdx.x) >> 6;  // global wave id = node
    int lane = threadIdx.x & 63;
    if (n >= NN) return;  // wave-uniform exit
    int r0 = row_ptr[n], r1 = row_ptr[n + 1];
    const int myh = (lane * VEC) >> 6;  // head owning this lane's channels

    float adn[H];
#pragma unroll
    for (int hh = 0; hh < H; ++hh) adn[hh] = a_d[n * H + hh];

    float denp[H];
#pragma unroll
    for (int hh = 0; hh < H; ++hh) denp[hh] = 0.f;
    float acc[VEC];
#pragma unroll
    for (int v = 0; v < VEC; ++v) acc[v] = 0.f;

    for (int base = r0; base < r1; base += 64) {
        int cnt = min(64, r1 - base);
        int idx = base + lane;
        bool act = idx < r1;
        int sl = act ? csr_src[idx] : 0;
        float exl[H];
#pragma unroll
        for (int hh = 0; hh < H; ++hh) {
            float e = a_s[sl * H + hh] + adn[hh];
            e = e > 0.f ? e : 0.2f * e;
            e = fminf(e, 60.f);
            float ex = __expf(e);
            exl[hh] = act ? ex : 0.f;
            denp[hh] += exl[hh];
        }
#pragma unroll 2
        for (int j = 0; j < cnt; ++j) {
            int s = __shfl(sl, j);
            float exv;
            if (H == 1) {
                exv = __shfl(exl[0], j);
            } else {
                float e0 = __shfl(exl[0], j);
                float e1 = __shfl(exl[1], j);
                exv = myh ? e1 : e0;
            }
            const u16* hp = h + (size_t)s * CH + lane * VEC;
            if (VEC == 2) {
                ushort2 hv = *(const ushort2*)hp;
                acc[0] += exv * b2f(hv.x);
                acc[1] += exv * b2f(hv.y);
            } else {
                acc[0] += exv * b2f(hp[0]);
            }
        }
    }

    // butterfly-reduce denominators across the wave
    float den[H];
#pragma unroll
    for (int hh = 0; hh < H; ++hh) {
        float dsum = denp[hh];
#pragma unroll
        for (int off = 32; off; off >>= 1) dsum += __shfl_xor(dsum, off);
        den[hh] = dsum;
    }
    float dn = den[myh];  // den >= exp(self-loop) > 0

    if (VEC == 2) {
        int c = lane * 2;
        float2 bv = *(const float2*)(bias + c);
        float v0 = acc[0] / dn + bv.x;
        float v1 = acc[1] / dn + bv.y;
        v0 = v0 > 0.f ? v0 : expm1f(v0);
        v1 = v1 > 0.f ? v1 : expm1f(v1);
        *(float2*)(outg + (size_t)n * CH + c) = make_float2(v0, v1);
    } else {
        float v0 = acc[0] / dn + bias[lane];
        v0 = v0 > 0.f ? v0 : expm1f(v0);
        if (HEAD) {
            // fused linear head: out[n,cls] = sum_lane v0 * Wl[lane,cls] + bl[cls]
#pragma unroll
            for (int cls = 0; cls < NCLS; ++cls) {
                float p = v0 * Wl[lane * NCLS + cls];
#pragma unroll
                for (int off = 32; off; off >>= 1) p += __shfl_xor(p, off);
                if (lane == cls) outh[(size_t)n * NCLS + cls] = p + bl[cls];
            }
        } else {
            outg[(size_t)n * CH + lane] = v0;
        }
    }
}

extern "C" void kernel_launch(void* const* d_in, const int* in_sizes, int n_in,
                              void* d_out, int out_size, void* d_ws, size_t ws_size,
                              hipStream_t stream) {
    const float* x   = (const float*)d_in[0];
    const int*   ei  = (const int*)d_in[1];
    const float* W1  = (const float*)d_in[2];
    const float* as1 = (const float*)d_in[3];
    const float* ad1 = (const float*)d_in[4];
    const float* b1  = (const float*)d_in[5];
    const float* W2  = (const float*)d_in[6];
    const float* as2 = (const float*)d_in[7];
    const float* ad2 = (const float*)d_in[8];
    const float* b2  = (const float*)d_in[9];
    const float* Wl  = (const float*)d_in[10];
    const float* bl  = (const float*)d_in[11];
    float* out = (float*)d_out;

    // ---- workspace layout: ~46 MB ----
    float* ws = (float*)d_ws;
    size_t o = 0;
    u16*   hb   = (u16*)(ws + o); o += (size_t)NN * 64;   // bf16 h1[N,128] / h2[N,64]
    float* g1   = ws + o;         o += (size_t)NN * 128;  // f32 gather-1 output
    float* a_s  = ws + o;         o += (size_t)NN * 2;
    float* a_d  = ws + o;         o += (size_t)NN * 2;
    int* ints = (int*)(ws + o);
    size_t io = 0;
    int* deg     = ints + io; io += NN;
    int* cursor  = ints + io; io += NN;
    int* excl    = ints + io; io += NN;
    int* bsums   = ints + io; io += 256;
    int* row_ptr = ints + io; io += NN + 1;
    int* csr_src = ints + io; io += EP;
    int* mode    = ints + io; io += 1;

    detect_mode_k<<<1, 64, 0, stream>>>(ei, mode);

    // ---- CSR of incoming edges (shared by both layers) ----
    hipMemsetAsync(deg, 0, NN * sizeof(int), stream);
    hipMemsetAsync(cursor, 0, NN * sizeof(int), stream);
    deg_count_k<<<(EP + 255) / 256, 256, 0, stream>>>(ei, mode, deg);
    scan1_k<<<NB_SCAN, 256, 0, stream>>>(deg, excl, bsums);
    scan2_k<<<1, 256, 0, stream>>>(bsums);
    scan3_k<<<NB_SCAN, 256, 0, stream>>>(excl, bsums, row_ptr);
    scatter_k<<<(EP + 255) / 256, 256, 0, stream>>>(ei, mode, row_ptr, cursor, csr_src);

    const int gatherBlocks = (NN + 3) / 4;  // 4 waves (nodes) per 256-thread block

    // ---- layer 1: GATConv(256 -> 64, heads=2, concat) + ELU ----
    dim3 grid1(2, (NN + 63) / 64);
    gemm_f32b_k<<<grid1, 256, 0, stream>>>(x, W1, hb, NN, 128, IN_DIM);   // h1 (bf16)
    att_scores_k<<<NN, 128, 0, stream>>>(hb, as1, ad1, a_s, a_d, 2);
    gat_gather_k<128, 2, false><<<gatherBlocks, 256, 0, stream>>>(
        row_ptr, csr_src, a_s, a_d, hb, b1, g1, nullptr, nullptr, nullptr);

    // ---- layer 2: GATConv(128 -> 64, heads=1) + ELU + fused head ----
    dim3 grid2(1, (NN + 63) / 64);
    gemm_f32b_k<<<grid2, 256, 0, stream>>>(g1, W2, hb, NN, 64, 128);      // h2 (bf16)
    att_scores_k<<<NN, 64, 0, stream>>>(hb, as2, ad2, a_s, a_d, 1);
    gat_gather_k<64, 1, true><<<gatherBlocks, 256, 0, stream>>>(
        row_ptr, csr_src, a_s, a_d, hb, b2, nullptr, Wl, bl, out);
}

// Round 7
// 515.453 us; speedup vs baseline: 9.0636x; 1.1505x over previous
//
#include <hip/hip_runtime.h>

#define NN 50000
#define NE 1600000
#define EP (NE + NN)   // edges + self loops
#define IN_DIM 256
#define HIDD 64
#define NCLS 10
#define NB_SCAN ((NN + 255) / 256)   // 196 blocks for the degree scan

typedef unsigned short u16;

__device__ __forceinline__ float b2f(u16 v) { return __uint_as_float(((unsigned)v) << 16); }
__device__ __forceinline__ u16 f2b(float f) {
    unsigned u = __float_as_uint(f);
    unsigned r = (u + 0x7FFFu + ((u >> 16) & 1u)) >> 16;
    return (u16)r;
}

// ---- edge_index dtype autodetect: int64 => all odd int32 words are 0 (ids < 2^31) ----
__global__ void detect_mode_k(const int* __restrict__ ei, int* __restrict__ mode) {
    int t = threadIdx.x;  // 64 threads
    int nz = 0;
#pragma unroll
    for (int k = 0; k < 4; ++k) {
        int i = t * 4 + k;
        if (ei[2 * i + 1] != 0) nz = 1;
    }
    unsigned long long b = __ballot(nz);
    if (t == 0) *mode = (b == 0ULL) ? 1 : 0;   // 1 = int64 layout
}

__device__ __forceinline__ void load_edge(const int* __restrict__ ei, int m, int g,
                                          int& s, int& d) {
    if (g < NE) {
        if (m) { s = ei[2 * (size_t)g]; d = ei[2 * ((size_t)NE + g)]; }
        else   { s = ei[g];             d = ei[NE + g]; }
    } else {
        s = d = g - NE;  // self loop
    }
    s = s < 0 ? 0 : (s >= NN ? NN - 1 : s);
    d = d < 0 ? 0 : (d >= NN ? NN - 1 : d);
}

// ---- CSR build ----
__global__ __launch_bounds__(256) void deg_count_k(const int* __restrict__ ei,
                                                   const int* __restrict__ mode,
                                                   int* __restrict__ deg) {
    int g = blockIdx.x * blockDim.x + threadIdx.x;
    if (g >= EP) return;
    int m = *mode, s, d;
    load_edge(ei, m, g, s, d);
    atomicAdd(&deg[d], 1);
}

__global__ __launch_bounds__(256) void scan1_k(const int* __restrict__ deg,
                                               int* __restrict__ excl,
                                               int* __restrict__ bsums) {
    __shared__ int sh[256];
    int t = threadIdx.x, b = blockIdx.x, i = b * 256 + t;
    int v = (i < NN) ? deg[i] : 0;
    sh[t] = v;
    __syncthreads();
    for (int off = 1; off < 256; off <<= 1) {
        int x = (t >= off) ? sh[t - off] : 0;
        __syncthreads();
        sh[t] += x;
        __syncthreads();
    }
    if (i < NN) excl[i] = sh[t] - v;
    if (t == 255) bsums[b] = sh[t];
}

__global__ __launch_bounds__(256) void scan2_k(int* __restrict__ bsums) {
    __shared__ int sh[256];
    int t = threadIdx.x;
    int v = (t < NB_SCAN) ? bsums[t] : 0;
    sh[t] = v;
    __syncthreads();
    for (int off = 1; off < 256; off <<= 1) {
        int x = (t >= off) ? sh[t - off] : 0;
        __syncthreads();
        sh[t] += x;
        __syncthreads();
    }
    if (t < NB_SCAN) bsums[t] = sh[t] - v;  // exclusive
}

__global__ __launch_bounds__(256) void scan3_k(const int* __restrict__ excl,
                                               const int* __restrict__ bsums,
                                               int* __restrict__ row_ptr) {
    int t = threadIdx.x, b = blockIdx.x, i = b * 256 + t;
    if (i < NN) row_ptr[i] = excl[i] + bsums[b];
    if (i == 0) row_ptr[NN] = EP;
}

__global__ __launch_bounds__(256) void scatter_k(const int* __restrict__ ei,
                                                 const int* __restrict__ mode,
                                                 const int* __restrict__ row_ptr,
                                                 int* __restrict__ cursor,
                                                 int* __restrict__ csr_src) {
    int g = blockIdx.x * blockDim.x + threadIdx.x;
    if (g >= EP) return;
    int m = *mode, s, d;
    load_edge(ei, m, g, s, d);
    int pos = atomicAdd(&cursor[d], 1);
    csr_src[row_ptr[d] + pos] = s;
}

// ---- tiled GEMM: C[M,Ncols] bf16 = A[M,K] f32 @ B[K,Ncols] f32 (f32 acc) ----
__global__ __launch_bounds__(256) void gemm_f32b_k(
    const float* __restrict__ A, const float* __restrict__ B, u16* __restrict__ C,
    int M, int Ncols, int K) {
    __shared__ float As[16][68];
    __shared__ float Bs[16][68];
    const int tid = threadIdx.x;
    const int m0 = blockIdx.y * 64, n0 = blockIdx.x * 64;
    const int ty = tid >> 4, tx = tid & 15;
    const int arow = tid >> 2, acol = (tid & 3) * 4;
    const int brow = tid >> 4, bcol = (tid & 15) * 4;
    float acc[4][4] = {};
    for (int k0 = 0; k0 < K; k0 += 16) {
        float4 a4 = make_float4(0.f, 0.f, 0.f, 0.f);
        if (m0 + arow < M)
            a4 = *(const float4*)(A + (size_t)(m0 + arow) * K + k0 + acol);
        float4 b4 = *(const float4*)(B + (size_t)(k0 + brow) * Ncols + n0 + bcol);
        __syncthreads();
        As[acol + 0][arow] = a4.x;
        As[acol + 1][arow] = a4.y;
        As[acol + 2][arow] = a4.z;
        As[acol + 3][arow] = a4.w;
        *(float4*)&Bs[brow][bcol] = b4;
        __syncthreads();
#pragma unroll
        for (int k = 0; k < 16; ++k) {
            float4 a = *(const float4*)&As[k][ty * 4];
            float4 b = *(const float4*)&Bs[k][tx * 4];
            float aa[4] = {a.x, a.y, a.z, a.w};
            float bb[4] = {b.x, b.y, b.z, b.w};
#pragma unroll
            for (int i = 0; i < 4; ++i)
#pragma unroll
                for (int j = 0; j < 4; ++j) acc[i][j] += aa[i] * bb[j];
        }
    }
#pragma unroll
    for (int i = 0; i < 4; ++i) {
        int row = m0 + ty * 4 + i;
        if (row < M) {
            ushort4 cv;
            cv.x = f2b(acc[i][0]); cv.y = f2b(acc[i][1]);
            cv.z = f2b(acc[i][2]); cv.w = f2b(acc[i][3]);
            *(ushort4*)(C + (size_t)row * Ncols + n0 + tx * 4) = cv;
        }
    }
}

// ---- per-node attention scores (bf16 h): one 64-lane wave per head ----
__global__ void att_scores_k(const u16* __restrict__ h, const float* __restrict__ asrc,
                             const float* __restrict__ adst, float* __restrict__ a_s,
                             float* __restrict__ a_d, int H) {
    int n = blockIdx.x, tid = threadIdx.x;  // blockDim.x == H*64
    float v = b2f(h[(size_t)n * blockDim.x + tid]);
    float ps = v * asrc[tid];
    float pd = v * adst[tid];
#pragma unroll
    for (int off = 32; off; off >>= 1) {
        ps += __shfl_down(ps, off);
        pd += __shfl_down(pd, off);
    }
    if ((tid & 63) == 0) {
        int hh = tid >> 6;
        a_s[(size_t)n * H + hh] = ps;
        a_d[(size_t)n * H + hh] = pd;
    }
}

// ---- fused gather (bf16 h): one WAVE per node; VEC = CH/64 bf16 per lane ----
// Lane-parallel softmax (one exp per edge across lanes). The j-loop is batched
// by 8: 8 shfl groups, then 8 INDEPENDENT h-row loads issued back-to-back
// (vmcnt MLP=8 per wave), then 8 fma groups. Tail edges carry ex=0, so
// over-read groups contribute exactly zero (row-0 loads are cached).
template <int CH, int H, bool HEAD>
__global__ __launch_bounds__(256) void gat_gather_k(
    const int* __restrict__ row_ptr, const int* __restrict__ csr_src,
    const float* __restrict__ a_s, const float* __restrict__ a_d,
    const u16* __restrict__ h, const float* __restrict__ bias,
    float* __restrict__ outg, const float* __restrict__ Wl,
    const float* __restrict__ bl, float* __restrict__ outh) {
    constexpr int VEC = CH / 64;
    constexpr int JB = 8;  // j-batch: loads in flight per wave
    int n = (blockIdx.x * blockDim.x + threadIdx.x) >> 6;  // global wave id = node
    int lane = threadIdx.x & 63;
    if (n >= NN) return;  // wave-uniform exit
    int r0 = row_ptr[n], r1 = row_ptr[n + 1];
    const bool hi = (VEC == 2) ? (lane >= 32) : false;  // head-1 lanes (VEC=2)
    const u16* hlane = h + lane * VEC;

    float adn[H];
#pragma unroll
    for (int hh = 0; hh < H; ++hh) adn[hh] = a_d[n * H + hh];

    float denp = 0.f;  // lane-partial denominator (head selected later)
    float dh0 = 0.f, dh1 = 0.f;
    float acc[VEC];
#pragma unroll
    for (int v = 0; v < VEC; ++v) acc[v] = 0.f;

    for (int base = r0; base < r1; base += 64) {
        int cnt = min(64, r1 - base);
        int idx = base + lane;
        bool act = idx < r1;
        int sl = act ? csr_src[idx] : 0;
        float exl0, exl1;
        {
            float e = a_s[sl * H + 0] + adn[0];
            e = e > 0.f ? e : 0.2f * e;
            e = fminf(e, 60.f);
            exl0 = act ? __expf(e) : 0.f;
            dh0 += exl0;
        }
        if (H == 2) {
            float e = a_s[sl * H + 1] + adn[1];
            e = e > 0.f ? e : 0.2f * e;
            e = fminf(e, 60.f);
            exl1 = act ? __expf(e) : 0.f;
            dh1 += exl1;
        }
        for (int j0 = 0; j0 < cnt; j0 += JB) {
            int ss[JB];
            float exv[JB];
#pragma unroll
            for (int i = 0; i < JB; ++i) {
                int j = j0 + i;
                ss[i] = __shfl(sl, j);
                if (H == 1) {
                    exv[i] = __shfl(exl0, j);
                } else {
                    float e0 = __shfl(exl0, j);
                    float e1 = __shfl(exl1, j);
                    exv[i] = hi ? e1 : e0;
                }
            }
            if (VEC == 2) {
                ushort2 hv[JB];
#pragma unroll
                for (int i = 0; i < JB; ++i)
                    hv[i] = *(const ushort2*)(hlane + (size_t)ss[i] * CH);
#pragma unroll
                for (int i = 0; i < JB; ++i) {
                    acc[0] += exv[i] * b2f(hv[i].x);
                    acc[1] += exv[i] * b2f(hv[i].y);
                }
            } else {
                u16 hv[JB];
#pragma unroll
                for (int i = 0; i < JB; ++i)
                    hv[i] = hlane[(size_t)ss[i] * CH];
#pragma unroll
                for (int i = 0; i < JB; ++i)
                    acc[0] += exv[i] * b2f(hv[i]);
            }
        }
    }

    // butterfly-reduce denominators across the wave
#pragma unroll
    for (int off = 32; off; off >>= 1) dh0 += __shfl_xor(dh0, off);
    float dn = dh0;
    if (H == 2) {
#pragma unroll
        for (int off = 32; off; off >>= 1) dh1 += __shfl_xor(dh1, off);
        dn = hi ? dh1 : dh0;
    }
    // dn >= exp(self-loop) > 0

    if (VEC == 2) {
        int c = lane * 2;
        float2 bv = *(const float2*)(bias + c);
        float v0 = acc[0] / dn + bv.x;
        float v1 = acc[1] / dn + bv.y;
        v0 = v0 > 0.f ? v0 : expm1f(v0);
        v1 = v1 > 0.f ? v1 : expm1f(v1);
        *(float2*)(outg + (size_t)n * CH + c) = make_float2(v0, v1);
    } else {
        float v0 = acc[0] / dn + bias[lane];
        v0 = v0 > 0.f ? v0 : expm1f(v0);
        if (HEAD) {
            // fused linear head: out[n,cls] = sum_lane v0 * Wl[lane,cls] + bl[cls]
#pragma unroll
            for (int cls = 0; cls < NCLS; ++cls) {
                float p = v0 * Wl[lane * NCLS + cls];
#pragma unroll
                for (int off = 32; off; off >>= 1) p += __shfl_xor(p, off);
                if (lane == cls) outh[(size_t)n * NCLS + cls] = p + bl[cls];
            }
        } else {
            outg[(size_t)n * CH + lane] = v0;
        }
    }
}

extern "C" void kernel_launch(void* const* d_in, const int* in_sizes, int n_in,
                              void* d_out, int out_size, void* d_ws, size_t ws_size,
                              hipStream_t stream) {
    const float* x   = (const float*)d_in[0];
    const int*   ei  = (const int*)d_in[1];
    const float* W1  = (const float*)d_in[2];
    const float* as1 = (const float*)d_in[3];
    const float* ad1 = (const float*)d_in[4];
    const float* b1  = (const float*)d_in[5];
    const float* W2  = (const float*)d_in[6];
    const float* as2 = (const float*)d_in[7];
    const float* ad2 = (const float*)d_in[8];
    const float* b2  = (const float*)d_in[9];
    const float* Wl  = (const float*)d_in[10];
    const float* bl  = (const float*)d_in[11];
    float* out = (float*)d_out;

    // ---- workspace layout: ~46 MB ----
    float* ws = (float*)d_ws;
    size_t o = 0;
    u16*   hb   = (u16*)(ws + o); o += (size_t)NN * 64;   // bf16 h1[N,128] / h2[N,64]
    float* g1   = ws + o;         o += (size_t)NN * 128;  // f32 gather-1 output
    float* a_s  = ws + o;         o += (size_t)NN * 2;
    float* a_d  = ws + o;         o += (size_t)NN * 2;
    int* ints = (int*)(ws + o);
    size_t io = 0;
    int* deg     = ints + io; io += NN;
    int* cursor  = ints + io; io += NN;
    int* excl    = ints + io; io += NN;
    int* bsums   = ints + io; io += 256;
    int* row_ptr = ints + io; io += NN + 1;
    int* csr_src = ints + io; io += EP;
    int* mode    = ints + io; io += 1;

    detect_mode_k<<<1, 64, 0, stream>>>(ei, mode);

    // ---- CSR of incoming edges (shared by both layers) ----
    hipMemsetAsync(deg, 0, NN * sizeof(int), stream);
    hipMemsetAsync(cursor, 0, NN * sizeof(int), stream);
    deg_count_k<<<(EP + 255) / 256, 256, 0, stream>>>(ei, mode, deg);
    scan1_k<<<NB_SCAN, 256, 0, stream>>>(deg, excl, bsums);
    scan2_k<<<1, 256, 0, stream>>>(bsums);
    scan3_k<<<NB_SCAN, 256, 0, stream>>>(excl, bsums, row_ptr);
    scatter_k<<<(EP + 255) / 256, 256, 0, stream>>>(ei, mode, row_ptr, cursor, csr_src);

    const int gatherBlocks = (NN + 3) / 4;  // 4 waves (nodes) per 256-thread block

    // ---- layer 1: GATConv(256 -> 64, heads=2, concat) + ELU ----
    dim3 grid1(2, (NN + 63) / 64);
    gemm_f32b_k<<<grid1, 256, 0, stream>>>(x, W1, hb, NN, 128, IN_DIM);   // h1 (bf16)
    att_scores_k<<<NN, 128, 0, stream>>>(hb, as1, ad1, a_s, a_d, 2);
    gat_gather_k<128, 2, false><<<gatherBlocks, 256, 0, stream>>>(
        row_ptr, csr_src, a_s, a_d, hb, b1, g1, nullptr, nullptr, nullptr);

    // ---- layer 2: GATConv(128 -> 64, heads=1) + ELU + fused head ----
    dim3 grid2(1, (NN + 63) / 64);
    gemm_f32b_k<<<grid2, 256, 0, stream>>>(g1, W2, hb, NN, 64, 128);      // h2 (bf16)
    att_scores_k<<<NN, 64, 0, stream>>>(hb, as2, ad2, a_s, a_d, 1);
    gat_gather_k<64, 1, true><<<gatherBlocks, 256, 0, stream>>>(
        row_ptr, csr_src, a_s, a_d, hb, b2, nullptr, Wl, bl, out);
}